// Round 1
// baseline (406.368 us; speedup 1.0000x reference)
//
#include <hip/hip_runtime.h>
#include <cstdint>
#include <cstddef>

#define V_SIZE 50257
#define D_DIM  1024
#define T_TOK  8192
#define NCHUNK 64
#define CCHUNK 128
#define NCAND  2048
#define NTILES 16
#define LOWR   32

typedef unsigned int  uint32;
typedef unsigned short u16;
typedef __attribute__((ext_vector_type(8))) short short8;
typedef __attribute__((ext_vector_type(4))) float f32x4;

__device__ __forceinline__ u16 f2bf(float f){
  uint32 u = __float_as_uint(f);
  return (u16)((u + 0x7FFFu + ((u >> 16) & 1u)) >> 16);
}
__device__ __forceinline__ uint32 key_of(float f){
  uint32 b = __float_as_uint(f);
  return b ^ ((uint32)((int)b >> 31) | 0x80000000u);
}
__device__ __forceinline__ float sigscale(const float* lsc){
  return 100.f / (1.f + __expf(-lsc[0])) + 1.f;
}
__device__ __forceinline__ float wred_sum(float v){
  #pragma unroll
  for (int m = 32; m >= 1; m >>= 1) v += __shfl_xor(v, m, 64);
  return v;
}
__device__ __forceinline__ float wred_max(float v){
  #pragma unroll
  for (int m = 32; m >= 1; m >>= 1) v = fmaxf(v, __shfl_xor(v, m, 64));
  return v;
}
__device__ __forceinline__ void gload_lds16(const void* g, void* l){
  __builtin_amdgcn_global_load_lds(
      (const __attribute__((address_space(1))) uint32*)g,
      (__attribute__((address_space(3))) uint32*)l, 16, 0, 0);
}
__device__ __forceinline__ void load_row16(const float* base, int lane, float* f){
  const float4* s4 = (const float4*)(base + lane * 16);
  float4 t0 = s4[0], t1 = s4[1], t2 = s4[2], t3 = s4[3];
  f[0]=t0.x; f[1]=t0.y; f[2]=t0.z;  f[3]=t0.w;
  f[4]=t1.x; f[5]=t1.y; f[6]=t1.z;  f[7]=t1.w;
  f[8]=t2.x; f[9]=t2.y; f[10]=t2.z; f[11]=t2.w;
  f[12]=t3.x; f[13]=t3.y; f[14]=t3.z; f[15]=t3.w;
}
__device__ __forceinline__ void store_bf16x16(u16* dst_base, int lane, const float* f){
  uint32 pk[8];
  #pragma unroll
  for (int i=0;i<8;++i) pk[i] = (uint32)f2bf(f[2*i]) | ((uint32)f2bf(f[2*i+1]) << 16);
  uint4* d = (uint4*)(dst_base + lane * 16);
  d[0] = make_uint4(pk[0],pk[1],pk[2],pk[3]);
  d[1] = make_uint4(pk[4],pk[5],pk[6],pk[7]);
}

// ---------------- vocab prep: fp32 -> bf16 + inv norms (full & low32) ----------
__global__ void __launch_bounds__(256)
vocab_prep(const float* __restrict__ emb, u16* __restrict__ emb16,
           float* __restrict__ invn_f, float* __restrict__ invn_l)
{
  const int wid = threadIdx.x >> 6, lane = threadIdx.x & 63;
  const int v = blockIdx.x * 4 + wid;
  if (v >= V_SIZE) return;
  float f[16];
  load_row16(emb + (size_t)v * D_DIM, lane, f);
  float ss = 0.f;
  #pragma unroll
  for (int k=0;k<16;++k) ss += f[k]*f[k];
  float fullss = wred_sum(ss);
  float lowss  = wred_sum(lane < 2 ? ss : 0.f);   // lanes 0,1 own elems 0..31
  store_bf16x16(emb16 + (size_t)v * D_DIM, lane, f);
  if (lane == 0){
    invn_f[v] = 1.f / fmaxf(sqrtf(fullss), 1e-12f);
    invn_l[v] = 1.f / fmaxf(sqrtf(lowss),  1e-12f);
  }
}

// ---------------- token prep: bf16 h, inv norms, per-chunk mean of norm'd low h
__global__ void __launch_bounds__(256)
token_prep(const float* __restrict__ h, u16* __restrict__ h16,
           float* __restrict__ invh_f, float* __restrict__ invh_l,
           float* __restrict__ h_mean)
{
  const int nchunk = blockIdx.x;
  const int tid = threadIdx.x, lane = tid & 63, wid = tid >> 6;
  __shared__ float hm[LOWR];
  if (tid < LOWR) hm[tid] = 0.f;
  __syncthreads();
  for (int i = 0; i < 32; ++i){
    const int loc = wid*32 + i;
    const int tok = nchunk * CCHUNK + loc;
    float f[16];
    load_row16(h + (size_t)tok * D_DIM, lane, f);
    float ss = 0.f;
    #pragma unroll
    for (int k=0;k<16;++k) ss += f[k]*f[k];
    float fullss = wred_sum(ss);
    float lowss  = wred_sum(lane < 2 ? ss : 0.f);
    float invf = 1.f / fmaxf(sqrtf(fullss), 1e-12f);
    float invl = 1.f / fmaxf(sqrtf(lowss),  1e-12f);
    store_bf16x16(h16 + (size_t)tok * D_DIM, lane, f);
    if (lane == 0){ invh_f[tok] = invf; invh_l[tok] = invl; }
    if (lane < 2){
      #pragma unroll
      for (int k=0;k<16;++k) atomicAdd(&hm[lane*16 + k], f[k] * invl * (1.f/128.f));
    }
  }
  __syncthreads();
  if (tid < LOWR) h_mean[nchunk * LOWR + tid] = hm[tid];
}

// ---------------- scan: scan_logits[n][v] = h_mean[n] . normalize(emb[v,:32]) --
__global__ void __launch_bounds__(256)
scan_kernel(const float* __restrict__ emb, const float* __restrict__ invn_l,
            const float* __restrict__ h_mean, float* __restrict__ scan)
{
  __shared__ float hm[NCHUNK * LOWR];
  for (int i = threadIdx.x; i < NCHUNK * LOWR; i += 256) hm[i] = h_mean[i];
  __syncthreads();
  const int v = blockIdx.x * 256 + threadIdx.x;
  if (v >= V_SIZE) return;
  float w[LOWR];
  const float4* s4 = (const float4*)(emb + (size_t)v * D_DIM);
  #pragma unroll
  for (int i=0;i<8;++i){
    float4 t = s4[i];
    w[4*i]=t.x; w[4*i+1]=t.y; w[4*i+2]=t.z; w[4*i+3]=t.w;
  }
  const float inv = invn_l[v];
  #pragma unroll
  for (int i=0;i<LOWR;++i) w[i] *= inv;
  for (int nn = 0; nn < NCHUNK; ++nn){
    float d = 0.f;
    #pragma unroll
    for (int l=0;l<LOWR;++l) d += w[l] * hm[nn*LOWR + l];
    scan[(size_t)nn * V_SIZE + v] = d;
  }
}

// ---------------- per-chunk radix top-K select (exact, index-ordered ties) ----
__global__ void __launch_bounds__(512)
topk_kernel(const float* __restrict__ scan, int* __restrict__ topidx,
            float* __restrict__ invc_f, float* __restrict__ invc_l,
            const float* __restrict__ invn_f, const float* __restrict__ invn_l)
{
  const int nchunk = blockIdx.x;
  const int tid = threadIdx.x, lane = tid & 63, wid = tid >> 6;
  const float* row = scan + (size_t)nchunk * V_SIZE;
  __shared__ uint32 hist[256];
  __shared__ uint32 s_bin, s_cum;
  __shared__ uint32 carry_gt, carry_eq;
  __shared__ uint32 wsg[8], wse[8];

  uint32 pref = 0, need = NCAND;
  for (int by = 3; by >= 0; --by){
    if (tid < 256) hist[tid] = 0;
    __syncthreads();
    const uint32 pmask = (by == 3) ? 0u : (0xFFFFFFFFu << ((by+1)*8));
    for (int v = tid; v < V_SIZE; v += 512){
      uint32 u = key_of(row[v]);
      if ((u & pmask) == pref) atomicAdd(&hist[(u >> (by*8)) & 255u], 1u);
    }
    __syncthreads();
    if (tid == 0){
      uint32 cum = 0; int b = 255;
      for (; b > 0; --b){ uint32 hc = hist[b]; if (cum + hc >= need) break; cum += hc; }
      s_bin = (uint32)b; s_cum = cum;
    }
    __syncthreads();
    pref |= (s_bin << (by*8));
    need -= s_cum;
    __syncthreads();
  }
  const uint32 U = pref;            // K-th largest key
  const uint32 G = NCAND - need;    // count strictly greater
  if (tid == 0){ carry_gt = 0; carry_eq = 0; }
  __syncthreads();
  for (int v0 = 0; v0 < V_SIZE; v0 += 512){
    const int v = v0 + tid;
    bool fgt = false, feq = false;
    if (v < V_SIZE){
      uint32 u = key_of(row[v]);
      fgt = (u > U); feq = (u == U);
    }
    const unsigned long long mg = __ballot(fgt);
    const unsigned long long me = __ballot(feq);
    const unsigned long long lm = (1ull << lane) - 1ull;
    const uint32 pg = (uint32)__popcll(mg & lm);
    const uint32 pe = (uint32)__popcll(me & lm);
    if (lane == 0){ wsg[wid] = (uint32)__popcll(mg); wse[wid] = (uint32)__popcll(me); }
    __syncthreads();
    uint32 og = carry_gt, oe = carry_eq;
    for (int w = 0; w < wid; ++w){ og += wsg[w]; oe += wse[w]; }
    if (fgt){
      const int o = nchunk * NCAND + (int)(og + pg);
      topidx[o] = v; invc_f[o] = invn_f[v]; invc_l[o] = invn_l[v];
    }
    if (feq){
      const uint32 posq = oe + pe;
      if (posq < need){
        const int o = nchunk * NCAND + (int)(G + posq);
        topidx[o] = v; invc_f[o] = invn_f[v]; invc_l[o] = invn_l[v];
      }
    }
    __syncthreads();
    if (tid == 0){
      uint32 sg = 0, se2 = 0;
      for (int w = 0; w < 8; ++w){ sg += wsg[w]; se2 += wse[w]; }
      carry_gt += sg; carry_eq += se2;
    }
    __syncthreads();
  }
}

// ---------------- bf16 MFMA GEMM (h x gathered cand rows) + fused partial LSE --
template<int KTOT, int BK>
__global__ void __launch_bounds__(256)
gemm_partial(const u16* __restrict__ h16, const u16* __restrict__ emb16,
             const int* __restrict__ topidx, const float* __restrict__ invh,
             const float* __restrict__ invc, const int* __restrict__ tgts,
             const float* __restrict__ lsc, float* __restrict__ partials)
{
  constexpr int NSTEP = KTOT / BK;
  constexpr int KK    = BK / 32;
  constexpr int LPR   = (BK * 2) / 16;  // lanes per staged row
  constexpr int RPC   = 64 / LPR;       // rows per global_load_lds call
  constexpr int CALLS = 32 / RPC;       // calls per wave (32 rows/wave)

  const int ntile = blockIdx.x, nchunk = blockIdx.y;
  const int tid = threadIdx.x, lane = tid & 63, wid = tid >> 6;
  const int wm = wid >> 1, wn = wid & 1;
  const int fq = lane >> 4, fr = lane & 15;

  __shared__ u16 As[CCHUNK * BK];
  __shared__ u16 Bs[CCHUNK * BK];
  __shared__ float s_invh[CCHUNK];
  __shared__ float s_invc[CCHUNK];
  __shared__ int   s_tgt[CCHUNK];
  __shared__ int   s_idx[CCHUNK];

  if (tid < CCHUNK){
    s_invh[tid] = invh[nchunk * CCHUNK + tid];
    s_tgt[tid]  = tgts[nchunk * CCHUNK + tid];
    int o = nchunk * NCAND + ntile * CCHUNK + tid;
    s_idx[tid]  = topidx[o];
    s_invc[tid] = invc[o];
  }

  const int rl = lane / LPR;
  const int cbyte = (lane % LPR) * 16;
  const char* aptr[CALLS];
  const char* bptr[CALLS];
  #pragma unroll
  for (int s = 0; s < CALLS; ++s){
    int row = wid * 32 + s * RPC + rl;
    aptr[s] = (const char*)h16 + ((size_t)(nchunk * CCHUNK + row)) * (D_DIM * 2) + cbyte;
    int cidx = topidx[nchunk * NCAND + ntile * CCHUNK + row];
    bptr[s] = (const char*)emb16 + (size_t)cidx * (D_DIM * 2) + cbyte;
  }

  f32x4 acc[4][4];
  #pragma unroll
  for (int m=0;m<4;++m)
    #pragma unroll
    for (int q=0;q<4;++q)
      acc[m][q] = (f32x4){0.f,0.f,0.f,0.f};

  for (int st = 0; st < NSTEP; ++st){
    const int koff = st * BK * 2;
    #pragma unroll
    for (int s = 0; s < CALLS; ++s){
      gload_lds16(aptr[s] + koff, (void*)&As[(wid*32 + s*RPC) * BK]);
      gload_lds16(bptr[s] + koff, (void*)&Bs[(wid*32 + s*RPC) * BK]);
    }
    __syncthreads();
    #pragma unroll
    for (int kk = 0; kk < KK; ++kk){
      const int ko = kk*32 + fq*8;
      short8 af[4], bf[4];
      #pragma unroll
      for (int m=0;m<4;++m) af[m] = *(const short8*)&As[(wm*64 + m*16 + fr)*BK + ko];
      #pragma unroll
      for (int q=0;q<4;++q) bf[q] = *(const short8*)&Bs[(wn*64 + q*16 + fr)*BK + ko];
      #pragma unroll
      for (int m=0;m<4;++m)
        #pragma unroll
        for (int q=0;q<4;++q)
          acc[m][q] = __builtin_amdgcn_mfma_f32_16x16x32_bf16(af[m], bf[q], acc[m][q], 0, 0, 0);
    }
    __syncthreads();
  }

  const float scale = sigscale(lsc);
  const float NEG = -__builtin_huge_valf();
  #pragma unroll
  for (int m=0;m<4;++m){
    #pragma unroll
    for (int j=0;j<4;++j){
      const int c = wm*64 + m*16 + fq*4 + j;
      const float ihs = s_invh[c] * scale;
      const int tg = s_tgt[c];
      float vals[4];
      #pragma unroll
      for (int q=0;q<4;++q){
        const int kl = wn*64 + q*16 + fr;
        float lg = acc[m][q][j] * ihs * s_invc[kl];
        vals[q] = (s_idx[kl] == tg) ? NEG : lg;
      }
      float lmax = fmaxf(fmaxf(vals[0], vals[1]), fmaxf(vals[2], vals[3]));
      #pragma unroll
      for (int ms=1; ms<16; ms<<=1) lmax = fmaxf(lmax, __shfl_xor(lmax, ms, 64));
      float se = 0.f;
      #pragma unroll
      for (int q=0;q<4;++q) se += __expf(vals[q] - lmax);
      #pragma unroll
      for (int ms=1; ms<16; ms<<=1) se += __shfl_xor(se, ms, 64);
      if (fr == 0){
        size_t pos = ((size_t)((nchunk*NTILES + ntile)*2 + wn) * CCHUNK + c) * 2;
        partials[pos]   = lmax;
        partials[pos+1] = se;
      }
    }
  }
}

// ---------------- merge partials + target term -> scalar loss ------------------
__global__ void __launch_bounds__(256)
merge_loss(const u16* __restrict__ h16, const u16* __restrict__ emb16,
           const int* __restrict__ tgts,
           const float* __restrict__ invh_f, const float* __restrict__ invh_l,
           const float* __restrict__ invn_f, const float* __restrict__ invn_l,
           const float* __restrict__ pm, const float* __restrict__ pa,
           const float* __restrict__ lsc, float* __restrict__ out)
{
  const int nchunk = blockIdx.x >> 2, quarter = blockIdx.x & 3;
  const int tid = threadIdx.x, lane = tid & 63, wid = tid >> 6;
  const float scale = sigscale(lsc);
  const float NEG = -__builtin_huge_valf();
  float wacc = 0.f;
  for (int i = 0; i < 8; ++i){
    const int loc = quarter*32 + wid*8 + i;
    const int tok = nchunk * CCHUNK + loc;
    const int t = tgts[tok];
    float part = 0.f;
    {
      const uint4* hp = (const uint4*)(h16 + (size_t)tok * D_DIM) + lane*2;
      const uint4* ep = (const uint4*)(emb16 + (size_t)t * D_DIM) + lane*2;
      uint4 hx = hp[0], hy = hp[1], ex = ep[0], ey = ep[1];
      uint32 hu[8] = {hx.x,hx.y,hx.z,hx.w,hy.x,hy.y,hy.z,hy.w};
      uint32 eu[8] = {ex.x,ex.y,ex.z,ex.w,ey.x,ey.y,ey.z,ey.w};
      #pragma unroll
      for (int k=0;k<8;++k){
        float h0 = __uint_as_float(hu[k] << 16);
        float h1 = __uint_as_float(hu[k] & 0xFFFF0000u);
        float e0 = __uint_as_float(eu[k] << 16);
        float e1 = __uint_as_float(eu[k] & 0xFFFF0000u);
        part += h0*e0 + h1*e1;
      }
    }
    float dfull = wred_sum(part);
    float dlow  = wred_sum(lane < 2 ? part : 0.f);
    float tful = dfull * invh_f[tok] * invn_f[t] * scale;
    float tlow = dlow  * invh_l[tok] * invn_l[t] * scale;

    float mi = NEG, si = 0.f, mia = NEG, sia = 0.f;
    if (lane < 32){
      size_t q = ((size_t)(nchunk*32 + lane) * CCHUNK + loc) * 2;
      mi  = pm[q]; si  = pm[q+1];
      mia = pa[q]; sia = pa[q+1];
    }
    float M  = wred_max(mi);
    float S  = wred_sum(lane < 32 ? si * __expf(mi - M) : 0.f);
    float M2 = fmaxf(M, tful);
    float lmain = __logf(S * __expf(M - M2) + __expf(tful - M2)) + M2 - tful;
    float Ma  = wred_max(mia);
    float Sa  = wred_sum(lane < 32 ? sia * __expf(mia - Ma) : 0.f);
    float M2a = fmaxf(Ma, tlow);
    float laux = __logf(Sa * __expf(Ma - M2a) + __expf(tlow - M2a)) + M2a - tlow;
    wacc += lmain + 0.2f * laux;
  }
  __shared__ float ws4[4];
  if (lane == 0) ws4[wid] = wacc;
  __syncthreads();
  if (tid == 0) atomicAdd(out, (ws4[0]+ws4[1]+ws4[2]+ws4[3]) * (1.f / (float)T_TOK));
}

// ---------------- host ---------------------------------------------------------
extern "C" void kernel_launch(void* const* d_in, const int* in_sizes, int n_in,
                              void* d_out, int out_size, void* d_ws, size_t ws_size,
                              hipStream_t stream)
{
  (void)in_sizes; (void)n_in;
  const float* h   = (const float*)d_in[0];
  const float* emb = (const float*)d_in[1];
  const float* lsc = (const float*)d_in[2];
  const int*   tgt = (const int*)d_in[3];
  float* out = (float*)d_out;

  uint8_t* p = (uint8_t*)d_ws;
  auto carve = [&](size_t n)->uint8_t*{
    uint8_t* r = p; p += (n + 255) & ~(size_t)255; return r;
  };
  u16*   emb16  = (u16*)  carve((size_t)V_SIZE * D_DIM * 2);
  float* invn_f = (float*)carve((size_t)V_SIZE * 4);
  float* invn_l = (float*)carve((size_t)V_SIZE * 4);
  u16*   h16    = (u16*)  carve((size_t)T_TOK * D_DIM * 2);
  float* invh_f = (float*)carve((size_t)T_TOK * 4);
  float* invh_l = (float*)carve((size_t)T_TOK * 4);
  float* h_mean = (float*)carve((size_t)NCHUNK * LOWR * 4);
  float* scan   = (float*)carve((size_t)NCHUNK * V_SIZE * 4);
  int*   topidx = (int*)  carve((size_t)NCHUNK * NCAND * 4);
  float* invc_f = (float*)carve((size_t)NCHUNK * NCAND * 4);
  float* invc_l = (float*)carve((size_t)NCHUNK * NCAND * 4);
  float* pm     = (float*)carve((size_t)NCHUNK * 32 * CCHUNK * 2 * 4);
  float* pa     = (float*)carve((size_t)NCHUNK * 32 * CCHUNK * 2 * 4);
  (void)ws_size;

  hipMemsetAsync(out, 0, (size_t)out_size * sizeof(float), stream);
  vocab_prep<<<dim3((V_SIZE + 3) / 4), dim3(256), 0, stream>>>(emb, emb16, invn_f, invn_l);
  token_prep<<<dim3(NCHUNK), dim3(256), 0, stream>>>(h, h16, invh_f, invh_l, h_mean);
  scan_kernel<<<dim3((V_SIZE + 255) / 256), dim3(256), 0, stream>>>(emb, invn_l, h_mean, scan);
  topk_kernel<<<dim3(NCHUNK), dim3(512), 0, stream>>>(scan, topidx, invc_f, invc_l, invn_f, invn_l);
  gemm_partial<1024, 64><<<dim3(NTILES, NCHUNK), dim3(256), 0, stream>>>(
      h16, emb16, topidx, invh_f, invc_f, tgt, lsc, pm);
  gemm_partial<32, 32><<<dim3(NTILES, NCHUNK), dim3(256), 0, stream>>>(
      h16, emb16, topidx, invh_l, invc_l, tgt, lsc, pa);
  merge_loss<<<dim3(NCHUNK * 4), dim3(256), 0, stream>>>(
      h16, emb16, tgt, invh_f, invh_l, invn_f, invn_l, pm, pa, lsc, out);
}